// Round 14
// baseline (1145.110 us; speedup 1.0000x reference)
//
#include <hip/hip_runtime.h>
#include <hip/hip_fp16.h>
#include <stdint.h>

typedef short bf16x8 __attribute__((ext_vector_type(8)));
typedef short bf16x4 __attribute__((ext_vector_type(4)));
typedef float f32x4 __attribute__((ext_vector_type(4)));
typedef unsigned short u16x4 __attribute__((ext_vector_type(4)));
typedef unsigned short u16x8 __attribute__((ext_vector_type(8)));

constexpr int NB = 8, NS = 1024, ND = 1024, NH = 16, NHD = 64;

static __device__ __forceinline__ unsigned short f2bf(float f) {
    union { float f; uint32_t u; } v; v.f = f;
    uint32_t r = (v.u + 0x7fffu + ((v.u >> 16) & 1u)) >> 16;
    return (unsigned short)r;
}

static __device__ __forceinline__ unsigned short f2h(float f) {
    return __half_as_ushort(__float2half(f));
}
static __device__ __forceinline__ float h2f(unsigned short h) {
    return __half2float(__ushort_as_half(h));
}

static __device__ __forceinline__ f32x4 mfma32(bf16x8 a, bf16x8 b, f32x4 c) {
    return __builtin_amdgcn_mfma_f32_16x16x32_bf16(a, b, c, 0, 0, 0);
}

// K=16 bf16 MFMA: A/B frag = 4 bf16 (k = (l>>4)*4 + e), C/D = f32x4.
static __device__ __forceinline__ f32x4 mfma16(bf16x4 a, bf16x4 b, f32x4 c) {
#if __has_builtin(__builtin_amdgcn_mfma_f32_16x16x16bf16_1k)
    return __builtin_amdgcn_mfma_f32_16x16x16bf16_1k(a, b, c, 0, 0, 0);
#elif __has_builtin(__builtin_amdgcn_mfma_f32_16x16x16_bf16)
    return __builtin_amdgcn_mfma_f32_16x16x16_bf16(a, b, c, 0, 0, 0);
#else
    asm volatile("v_mfma_f32_16x16x16_bf16 %0, %1, %2, %0\n\ts_nop 7\n\ts_nop 7"
                 : "+v"(c) : "v"(a), "v"(b));
    return c;
#endif
}

static __device__ __forceinline__ bool mask_at(const void* m, size_t idx, int ms) {
    if (ms == 4) return ((const unsigned int*)m)[idx] != 0u;
    return ((const unsigned char*)m)[idx] != 0;
}

__global__ void detect_mask(const unsigned int* __restrict__ m, int* __restrict__ flag) {
    int l = threadIdx.x;
    bool bad = false;
    for (int i = l; i < 1024; i += 64) {
        unsigned int w = m[i];
        bad |= (w > 1u && w != 0x3f800000u);
    }
    bad = (bool)__any(bad);
    if (l == 0) *flag = bad ? 1 : 4;
}

// f32 [M][1024] -> fragment-packed bf16 [M/16][32 kt][64 lane][8]
__global__ __launch_bounds__(256) void cvt_frag(const float* __restrict__ in,
                                                unsigned short* __restrict__ out, int n8) {
    int stride = gridDim.x * blockDim.x;
    for (int idx = blockIdx.x * blockDim.x + threadIdx.x; idx < n8; idx += stride) {
        const float4* p = (const float4*)in + 2 * (size_t)idx;
        float4 a = p[0], b = p[1];
        u16x8 o;
        o[0] = f2bf(a.x); o[1] = f2bf(a.y); o[2] = f2bf(a.z); o[3] = f2bf(a.w);
        o[4] = f2bf(b.x); o[5] = f2bf(b.y); o[6] = f2bf(b.z); o[7] = f2bf(b.w);
        int m = idx >> 7, c8 = idx & 127;
        int kt = c8 >> 2, sub = c8 & 3;
        int lane = (m & 15) + 16 * sub;
        size_t slot = ((size_t)(m >> 4) * 32 + kt) * 64 + lane;
        *(u16x8*)(out + slot * 8) = o;
    }
}

// C(M x N) = A(MxK)*W(NxK)^T + bias, inputs fragment-packed [*/16][32][64][8].
// mode 0: QKf[b][h][s/16][d32][64][8]           (K=32 frag layout for QK^T)
// mode 1: Vf [b][h][tp32][dt4][64][4+4]         (K=16 frag pairs for PV; k-dim = s)
__global__ __launch_bounds__(256) void proj_gemm(const unsigned short* __restrict__ Af,
                                                 const unsigned short* __restrict__ Wf,
                                                 const float* __restrict__ bias,
                                                 unsigned short* __restrict__ C, int mode) {
    int l = threadIdx.x & 63, w = threadIdx.x >> 6;
    int lr = l & 15, lg = l >> 4;
    int m_base = blockIdx.x * 128 + (w >> 1) * 64;
    int n_base = blockIdx.y * 128 + (w & 1) * 64;
    int mtg0 = m_base >> 4, ntg0 = n_base >> 4;
    f32x4 acc[4][4] = {};
    for (int kt = 0; kt < 32; kt++) {
        bf16x8 af[4], bfr[4];
        #pragma unroll
        for (int mt = 0; mt < 4; mt++)
            af[mt] = *(const bf16x8*)(Af + (((size_t)(mtg0 + mt) * 32 + kt) * 64 + l) * 8);
        #pragma unroll
        for (int nt = 0; nt < 4; nt++)
            bfr[nt] = *(const bf16x8*)(Wf + (((size_t)(ntg0 + nt) * 32 + kt) * 64 + l) * 8);
        #pragma unroll
        for (int mt = 0; mt < 4; mt++) {
            #pragma unroll
            for (int nt = 0; nt < 4; nt++)
                acc[mt][nt] = mfma32(af[mt], bfr[nt], acc[mt][nt]);
        }
    }
    #pragma unroll
    for (int mt = 0; mt < 4; mt++) {
        #pragma unroll
        for (int nt = 0; nt < 4; nt++) {
            int col = n_base + nt * 16 + lr;          // output feature n
            int row0 = m_base + mt * 16 + lg * 4;     // flattened (b*S + s)
            float bv = bias[col];
            int b = row0 >> 10;
            int h = col >> 6;
            if (mode == 0) {
                int st = (row0 & 1023) >> 4;
                int d32 = (col & 63) >> 5;
                int sub = (col & 31) >> 3;
                int e = col & 7;
                size_t base = ((((size_t)(b * NH + h) * 64 + st) * 2 + d32) * 64) * 8;
                #pragma unroll
                for (int r = 0; r < 4; r++) {
                    int lane = lg * 4 + r + 16 * sub;
                    C[base + (size_t)lane * 8 + e] = f2bf(acc[mt][nt][r] + bv);
                }
            } else {
                int s0 = row0 & 1023;        // lg*4-aligned
                int tg = s0 >> 4;            // global 16-k tile index (0..63)
                int tp = tg >> 1, half = tg & 1;
                int dd = col & 63;
                int dt = dd >> 4;
                int lane = (dd & 15) + 16 * lg;
                u16x4 pk;
                #pragma unroll
                for (int r = 0; r < 4; r++) pk[r] = f2bf(acc[mt][nt][r] + bv);
                size_t addr = ((((size_t)(b * NH + h) * 32 + tp) * 4 + dt) * 64 + lane) * 8
                              + half * 4;
                *(u16x4*)(C + addr) = pk;
            }
        }
    }
}

// TR = (1-l1)*l2*time_attn + l1*rel_attn, stored F16 fragment-packed:
// TRh[b][qt][t64][lane64][4 x f16]  (t covers k=t*16+lg*4, lane=(q&15)+16*lg)
// PMf[b][qt][qr16][32 words]        full-row packed mask per q-row
__global__ __launch_bounds__(256) void tr_kernel(const float* __restrict__ rel,
                                                 const float* __restrict__ ts,
                                                 const void* __restrict__ maskp,
                                                 const int* __restrict__ msflag,
                                                 const float* __restrict__ l1p,
                                                 const float* __restrict__ l2p,
                                                 unsigned short* __restrict__ TRh,
                                                 uint32_t* __restrict__ PMf) {
    __shared__ float s_tm[4], s_rm[4], s_ts[4], s_rs[4];
    __shared__ unsigned char s_nib[256];
    int row = blockIdx.x;               // b*S + q
    int t = threadIdx.x, w = t >> 6, l = t & 63;
    int ms = *msflag;
    size_t base = (size_t)row * NS;
    float4 r4 = ((const float4*)(rel + base))[t];
    float4 t4 = ((const float4*)(ts + base))[t];
    float rr[4], tt[4];
    *(float4*)rr = r4; *(float4*)tt = t4;
    float tv[4], rv[4];
    unsigned nib = 0;
    float tmx = -3.0e38f, rmx = -3.0e38f;
    #pragma unroll
    for (int j = 0; j < 4; j++) {
        bool m = mask_at(maskp, base + t * 4 + j, ms);
        nib |= (m ? 1u : 0u) << j;
        tv[j] = m ? -100000.0f : __expf(-fabsf(tt[j]));
        float rm_ = m ? rr[j] : 0.0f;
        rv[j] = (rm_ == 0.0f) ? -100000.0f : rm_;
        tmx = fmaxf(tmx, tv[j]); rmx = fmaxf(rmx, rv[j]);
    }
    s_nib[t] = (unsigned char)nib;
    #pragma unroll
    for (int off = 1; off < 64; off <<= 1) {
        tmx = fmaxf(tmx, __shfl_xor(tmx, off));
        rmx = fmaxf(rmx, __shfl_xor(rmx, off));
    }
    if (l == 0) { s_tm[w] = tmx; s_rm[w] = rmx; }
    __syncthreads();
    tmx = fmaxf(fmaxf(s_tm[0], s_tm[1]), fmaxf(s_tm[2], s_tm[3]));
    rmx = fmaxf(fmaxf(s_rm[0], s_rm[1]), fmaxf(s_rm[2], s_rm[3]));
    float te[4], re[4], tsum = 0.f, rsum = 0.f;
    #pragma unroll
    for (int j = 0; j < 4; j++) {
        te[j] = __expf(tv[j] - tmx); tsum += te[j];
        re[j] = __expf(rv[j] - rmx); rsum += re[j];
    }
    #pragma unroll
    for (int off = 1; off < 64; off <<= 1) {
        tsum += __shfl_xor(tsum, off);
        rsum += __shfl_xor(rsum, off);
    }
    if (l == 0) { s_ts[w] = tsum; s_rs[w] = rsum; }
    __syncthreads();
    tsum = s_ts[0] + s_ts[1] + s_ts[2] + s_ts[3];
    rsum = s_rs[0] + s_rs[1] + s_rs[2] + s_rs[3];
    float l1 = *l1p, l2 = *l2p;
    float ti = ((1.0f - l1) * l2) / tsum;
    float ri = l1 / rsum;
    u16x4 oh;
    oh[0] = f2h(te[0] * ti + re[0] * ri);
    oh[1] = f2h(te[1] * ti + re[1] * ri);
    oh[2] = f2h(te[2] * ti + re[2] * ri);
    oh[3] = f2h(te[3] * ti + re[3] * ri);
    int b = row >> 10, q = row & 1023;
    int qt = q >> 4, qr = q & 15;
    size_t slot = ((size_t)(b * 64 + qt) * 64 + (t >> 2)) * 64 + (qr + 16 * (t & 3));
    ((u16x4*)TRh)[slot] = oh;
    if (t < 32) {
        uint32_t word = 0;
        #pragma unroll
        for (int i = 0; i < 8; i++)
            word |= ((uint32_t)s_nib[t * 8 + i]) << (i * 4);
        PMf[((size_t)(b * 64 + qt) * 16 + qr) * 32 + t] = word;
    }
}

// Fused scores+softmax(no-max)+blend+PV, ONE WAVE per block, zero barriers, zero LDS.
// FULLY UNROLLED passes + hoisted PM words + __launch_bounds__(64,2):
// straight-line code lets the scheduler hoist loads across former iteration
// boundaries (R6-R13 dynamic loops confined MLP to ~6 loads in flight; VGPR=60).
// Swizzle: b pinned to XCD, qt innermost (R10 known-good locality).
__global__ __launch_bounds__(64, 2) void att_pv_kernel(const unsigned short* __restrict__ Qf,
                                                       const unsigned short* __restrict__ Kf,
                                                       const uint32_t* __restrict__ PMf,
                                                       const unsigned short* __restrict__ TRh,
                                                       const float* __restrict__ l1p,
                                                       const float* __restrict__ l2p,
                                                       const unsigned short* __restrict__ Vf,
                                                       float* __restrict__ probOut,
                                                       float* __restrict__ outp) {
    int bid = blockIdx.x;
    int swz = ((bid & 7) << 10) | (bid >> 3);   // XCD-aware, bijective (8192 = 8*1024)
    int qt = swz & 63;
    int h = (swz >> 6) & 15;
    int b = swz >> 10;
    int l = threadIdx.x, lr = l & 15, lg = l >> 4;
    int q0 = qt * 16;
    int q = q0 + lr;                   // this lane's q-row
    size_t bh = (size_t)(b * NH + h);

    const unsigned short* qf = Qf + (((bh * 64 + qt) * 2) * 64 + l) * 8;
    bf16x8 bq0 = *(const bf16x8*)(qf);
    bf16x8 bq1 = *(const bf16x8*)(qf + 64 * 8);

    const unsigned short* kfb = Kf + ((bh * 64 * 2) * 64) * 8 + (size_t)l * 8;
    const uint32_t* pmrow = PMf + ((size_t)(b * 64 + qt) * 16 + lr) * 32;

    // hoist all 32 packed-mask words (reused by both passes; static after unroll)
    uint32_t pm[32];
    #pragma unroll
    for (int j = 0; j < 8; j++)
        *(uint4*)(pm + j * 4) = *(const uint4*)(pmrow + j * 4);

    // ---- pass 1: row sums (fully unrolled: loads hoistable across tiles) ----
    float sm = 0.f;
    #pragma unroll
    for (int t = 0; t < 64; t++) {
        const unsigned short* kp = kfb + (size_t)t * 1024;
        bf16x8 a0 = *(const bf16x8*)kp;
        bf16x8 a1 = *(const bf16x8*)(kp + 512);
        f32x4 acc = {};
        acc = mfma32(a0, bq0, acc);
        acc = mfma32(a1, bq1, acc);
        uint32_t word = pm[t >> 1];
        int shift = (t & 1) * 16 + lg * 4;
        #pragma unroll
        for (int r = 0; r < 4; r++) {
            bool m = (word >> (shift + r)) & 1u;
            sm += m ? 0.0f : __expf(acc[r] * 0.125f);
        }
    }
    sm += __shfl_xor(sm, 16);
    sm += __shfl_xor(sm, 32);
    float l1 = *l1p, l2 = *l2p;
    float rinv = ((1.0f - l1) * (1.0f - l2)) / sm;

    // ---- pass 2: recompute + blend + prob store + PV (fully unrolled) ----
    float* po = probOut + bh * NS * NS + (size_t)q * NS;
    const u16x4* trh = (const u16x4*)TRh + ((size_t)(b * 64 + qt) * 64) * 64 + l;
    const unsigned short* vf = Vf + (bh * 32 * 4 * 64) * 8 + (size_t)l * 8;
    f32x4 acc2[4] = {};
    #pragma unroll
    for (int tp = 0; tp < 32; tp++) {
        bf16x4 pf0, pf1;
        #pragma unroll
        for (int hf = 0; hf < 2; hf++) {
            int t = tp * 2 + hf;
            const unsigned short* kp = kfb + (size_t)t * 1024;
            bf16x8 a0 = *(const bf16x8*)kp;
            bf16x8 a1 = *(const bf16x8*)(kp + 512);
            f32x4 acc = {};
            acc = mfma32(a0, bq0, acc);
            acc = mfma32(a1, bq1, acc);
            uint32_t word = pm[t >> 1];
            int shift = (t & 1) * 16 + lg * 4;
            u16x4 tr4 = trh[(size_t)t * 64];
            float4 o;
            float e0 = ((word >> (shift + 0)) & 1u) ? 0.f : __expf(acc[0] * 0.125f);
            float e1 = ((word >> (shift + 1)) & 1u) ? 0.f : __expf(acc[1] * 0.125f);
            float e2 = ((word >> (shift + 2)) & 1u) ? 0.f : __expf(acc[2] * 0.125f);
            float e3 = ((word >> (shift + 3)) & 1u) ? 0.f : __expf(acc[3] * 0.125f);
            o.x = e0 * rinv + h2f(tr4[0]);
            o.y = e1 * rinv + h2f(tr4[1]);
            o.z = e2 * rinv + h2f(tr4[2]);
            o.w = e3 * rinv + h2f(tr4[3]);
            *(float4*)(po + t * 16 + lg * 4) = o;
            bf16x4 pk;
            pk[0] = (short)f2bf(o.x); pk[1] = (short)f2bf(o.y);
            pk[2] = (short)f2bf(o.z); pk[3] = (short)f2bf(o.w);
            if (hf == 0) pf0 = pk; else pf1 = pk;
        }
        #pragma unroll
        for (int dt = 0; dt < 4; dt++) {
            bf16x8 vv = *(const bf16x8*)(vf + (size_t)(tp * 4 + dt) * 512);
            bf16x4 v0 = __builtin_shufflevector(vv, vv, 0, 1, 2, 3);
            bf16x4 v1 = __builtin_shufflevector(vv, vv, 4, 5, 6, 7);
            acc2[dt] = mfma16(v0, pf0, acc2[dt]);
            acc2[dt] = mfma16(v1, pf1, acc2[dt]);
        }
    }
    // out: d = dt*16 + lg*4 + r, row q
    float* orow = outp + ((size_t)b * NS + q) * ND + h * NHD + lg * 4;
    #pragma unroll
    for (int dt = 0; dt < 4; dt++) {
        float4 ov;
        ov.x = acc2[dt][0]; ov.y = acc2[dt][1]; ov.z = acc2[dt][2]; ov.w = acc2[dt][3];
        *(float4*)(orow + dt * 16) = ov;
    }
}

extern "C" void kernel_launch(void* const* d_in, const int* in_sizes, int n_in,
                              void* d_out, int out_size, void* d_ws, size_t ws_size,
                              hipStream_t stream) {
    const float* query = (const float*)d_in[0];
    const float* key   = (const float*)d_in[1];
    const float* value = (const float*)d_in[2];
    const float* rel   = (const float*)d_in[3];
    const float* ts    = (const float*)d_in[4];
    const void*  mask  = d_in[5];
    const float* l1p   = (const float*)d_in[6];
    const float* l2p   = (const float*)d_in[7];
    const float* Wq = (const float*)d_in[9];
    const float* bq = (const float*)d_in[10];
    const float* Wk = (const float*)d_in[11];
    const float* bk = (const float*)d_in[12];
    const float* Wv = (const float*)d_in[13];
    const float* bv = (const float*)d_in[14];

    char* ws = (char*)d_ws;
    const size_t SZ = (size_t)NB * NS * ND * 2;   // 16.78 MB
    unsigned short* Qf  = (unsigned short*)(ws);
    unsigned short* Kf  = (unsigned short*)(ws + SZ);
    unsigned short* Vf  = (unsigned short*)(ws + 2 * SZ);
    unsigned short* Afq = (unsigned short*)(ws + 3 * SZ);
    unsigned short* Afk = (unsigned short*)(ws + 4 * SZ);
    unsigned short* Afv = (unsigned short*)(ws + 5 * SZ);
    unsigned short* Wfq = (unsigned short*)(ws + 6 * SZ);
    unsigned short* Wfk = (unsigned short*)(ws + 6 * SZ + 2u * 1024 * 1024);
    unsigned short* Wfv = (unsigned short*)(ws + 6 * SZ + 4u * 1024 * 1024);
    int* msflag         = (int*)(ws + 6 * SZ + 6u * 1024 * 1024);
    uint32_t* PMf       = (uint32_t*)(ws + 6 * SZ + 8u * 1024 * 1024);  // 1 MB
    // TRh (f16, 16.78 MB = SZ) reuses Afq — written only AFTER projections finish.
    unsigned short* TRh = (unsigned short*)(ws + 3 * SZ);

    detect_mask<<<1, 64, 0, stream>>>((const unsigned int*)mask, msflag);

    const int nX8 = NB * NS * ND / 8;
    const int nW8 = 1024 * 1024 / 8;
    cvt_frag<<<1024, 256, 0, stream>>>(query, Afq, nX8);
    cvt_frag<<<1024, 256, 0, stream>>>(key,   Afk, nX8);
    cvt_frag<<<1024, 256, 0, stream>>>(value, Afv, nX8);
    cvt_frag<<<256, 256, 0, stream>>>(Wq, Wfq, nW8);
    cvt_frag<<<256, 256, 0, stream>>>(Wk, Wfk, nW8);
    cvt_frag<<<256, 256, 0, stream>>>(Wv, Wfv, nW8);

    dim3 pg(64, 8);
    proj_gemm<<<pg, 256, 0, stream>>>(Afq, Wfq, bq, Qf, 0);
    proj_gemm<<<pg, 256, 0, stream>>>(Afk, Wfk, bk, Kf, 0);
    proj_gemm<<<pg, 256, 0, stream>>>(Afv, Wfv, bv, Vf, 1);

    tr_kernel<<<NB * NS, 256, 0, stream>>>(rel, ts, mask, msflag, l1p, l2p, TRh, PMf);

    float* outp = (float*)d_out;
    float* probOut = outp + (size_t)NB * NS * ND;
    att_pv_kernel<<<NB * NH * (NS / 16), 64, 0, stream>>>(Qf, Kf, PMf, TRh, l1p, l2p, Vf,
                                                          probOut, outp);
}

// Round 15
// 514.105 us; speedup vs baseline: 2.2274x; 2.2274x over previous
//
#include <hip/hip_runtime.h>
#include <hip/hip_fp16.h>
#include <stdint.h>

typedef short bf16x8 __attribute__((ext_vector_type(8)));
typedef short bf16x4 __attribute__((ext_vector_type(4)));
typedef float f32x4 __attribute__((ext_vector_type(4)));
typedef unsigned short u16x4 __attribute__((ext_vector_type(4)));
typedef unsigned short u16x8 __attribute__((ext_vector_type(8)));

constexpr int NB = 8, NS = 1024, ND = 1024, NH = 16, NHD = 64;

static __device__ __forceinline__ unsigned short f2bf(float f) {
    union { float f; uint32_t u; } v; v.f = f;
    uint32_t r = (v.u + 0x7fffu + ((v.u >> 16) & 1u)) >> 16;
    return (unsigned short)r;
}

static __device__ __forceinline__ unsigned short f2h(float f) {
    return __half_as_ushort(__float2half(f));
}
static __device__ __forceinline__ float h2f(unsigned short h) {
    return __half2float(__ushort_as_half(h));
}

static __device__ __forceinline__ f32x4 mfma32(bf16x8 a, bf16x8 b, f32x4 c) {
    return __builtin_amdgcn_mfma_f32_16x16x32_bf16(a, b, c, 0, 0, 0);
}

// K=16 bf16 MFMA: A/B frag = 4 bf16 (k = (l>>4)*4 + e), C/D = f32x4.
static __device__ __forceinline__ f32x4 mfma16(bf16x4 a, bf16x4 b, f32x4 c) {
#if __has_builtin(__builtin_amdgcn_mfma_f32_16x16x16bf16_1k)
    return __builtin_amdgcn_mfma_f32_16x16x16bf16_1k(a, b, c, 0, 0, 0);
#elif __has_builtin(__builtin_amdgcn_mfma_f32_16x16x16_bf16)
    return __builtin_amdgcn_mfma_f32_16x16x16_bf16(a, b, c, 0, 0, 0);
#else
    asm volatile("v_mfma_f32_16x16x16_bf16 %0, %1, %2, %0\n\ts_nop 7\n\ts_nop 7"
                 : "+v"(c) : "v"(a), "v"(b));
    return c;
#endif
}

static __device__ __forceinline__ bool mask_at(const void* m, size_t idx, int ms) {
    if (ms == 4) return ((const unsigned int*)m)[idx] != 0u;
    return ((const unsigned char*)m)[idx] != 0;
}

__global__ void detect_mask(const unsigned int* __restrict__ m, int* __restrict__ flag) {
    int l = threadIdx.x;
    bool bad = false;
    for (int i = l; i < 1024; i += 64) {
        unsigned int w = m[i];
        bad |= (w > 1u && w != 0x3f800000u);
    }
    bad = (bool)__any(bad);
    if (l == 0) *flag = bad ? 1 : 4;
}

// f32 [M][1024] -> fragment-packed bf16 [M/16][32 kt][64 lane][8].
// One wave per (mg,kt) unit: writes one contiguous 1KB block per wave
// (old layout wrote 16B per 64B line -> ~4x write amplification).
__global__ __launch_bounds__(256) void cvt_frag(const float* __restrict__ in,
                                                unsigned short* __restrict__ out, int nunits) {
    int nw = (gridDim.x * blockDim.x) >> 6;
    int w = (blockIdx.x * blockDim.x + threadIdx.x) >> 6;
    int l = threadIdx.x & 63;
    int mr = l & 15, sub = l >> 4;
    for (int u = w; u < nunits; u += nw) {
        int mg = u >> 5, kt = u & 31;
        const float4* p = (const float4*)(in + ((size_t)(mg * 16 + mr)) * 1024 + kt * 32 + sub * 8);
        float4 a = p[0], b = p[1];
        u16x8 o;
        o[0] = f2bf(a.x); o[1] = f2bf(a.y); o[2] = f2bf(a.z); o[3] = f2bf(a.w);
        o[4] = f2bf(b.x); o[5] = f2bf(b.y); o[6] = f2bf(b.z); o[7] = f2bf(b.w);
        *(u16x8*)(out + ((size_t)u * 64 + l) * 8) = o;
    }
}

// C(M x N) = A(MxK)*W(NxK)^T + bias, inputs fragment-packed [*/16][32][64][8].
// Grid: x = n-panel (0..7), y = m-panel (0..63) -> XCD i pins Wf panel i in L2
// (256KB) and streams Af (L3-served). [x=m ordering put 4MB per XCD = thrash]
// mode 0: QKf[b][h][s/16][d32][64][8]           (K=32 frag layout for QK^T)
// mode 1: Vf [b][h][tp32][dt4][64][4+4]         (K=16 frag pairs for PV; k-dim = s)
__global__ __launch_bounds__(256) void proj_gemm(const unsigned short* __restrict__ Af,
                                                 const unsigned short* __restrict__ Wf,
                                                 const float* __restrict__ bias,
                                                 unsigned short* __restrict__ C, int mode) {
    int l = threadIdx.x & 63, w = threadIdx.x >> 6;
    int lr = l & 15, lg = l >> 4;
    int m_base = blockIdx.y * 128 + (w >> 1) * 64;
    int n_base = blockIdx.x * 128 + (w & 1) * 64;
    int mtg0 = m_base >> 4, ntg0 = n_base >> 4;
    f32x4 acc[4][4] = {};
    for (int kt = 0; kt < 32; kt++) {
        bf16x8 af[4], bfr[4];
        #pragma unroll
        for (int mt = 0; mt < 4; mt++)
            af[mt] = *(const bf16x8*)(Af + (((size_t)(mtg0 + mt) * 32 + kt) * 64 + l) * 8);
        #pragma unroll
        for (int nt = 0; nt < 4; nt++)
            bfr[nt] = *(const bf16x8*)(Wf + (((size_t)(ntg0 + nt) * 32 + kt) * 64 + l) * 8);
        #pragma unroll
        for (int mt = 0; mt < 4; mt++) {
            #pragma unroll
            for (int nt = 0; nt < 4; nt++)
                acc[mt][nt] = mfma32(af[mt], bfr[nt], acc[mt][nt]);
        }
    }
    #pragma unroll
    for (int mt = 0; mt < 4; mt++) {
        #pragma unroll
        for (int nt = 0; nt < 4; nt++) {
            int col = n_base + nt * 16 + lr;          // output feature n
            int row0 = m_base + mt * 16 + lg * 4;     // flattened (b*S + s)
            float bv = bias[col];
            int b = row0 >> 10;
            int h = col >> 6;
            if (mode == 0) {
                int st = (row0 & 1023) >> 4;
                int d32 = (col & 63) >> 5;
                int sub = (col & 31) >> 3;
                int e = col & 7;
                size_t base = ((((size_t)(b * NH + h) * 64 + st) * 2 + d32) * 64) * 8;
                #pragma unroll
                for (int r = 0; r < 4; r++) {
                    int lane = lg * 4 + r + 16 * sub;
                    C[base + (size_t)lane * 8 + e] = f2bf(acc[mt][nt][r] + bv);
                }
            } else {
                int s0 = row0 & 1023;        // lg*4-aligned
                int tg = s0 >> 4;            // global 16-k tile index (0..63)
                int tp = tg >> 1, half = tg & 1;
                int dd = col & 63;
                int dt = dd >> 4;
                int lane = (dd & 15) + 16 * lg;
                u16x4 pk;
                #pragma unroll
                for (int r = 0; r < 4; r++) pk[r] = f2bf(acc[mt][nt][r] + bv);
                size_t addr = ((((size_t)(b * NH + h) * 32 + tp) * 4 + dt) * 64 + lane) * 8
                              + half * 4;
                *(u16x4*)(C + addr) = pk;
            }
        }
    }
}

// TR = (1-l1)*l2*time_attn + l1*rel_attn, stored F16 fragment-packed:
// TRh[b][qt][t64][lane64][4 x f16]  (t covers k=t*16+lg*4, lane=(q&15)+16*lg)
// PMf[b][qt][qr16][32 words]        full-row packed mask per q-row
__global__ __launch_bounds__(256) void tr_kernel(const float* __restrict__ rel,
                                                 const float* __restrict__ ts,
                                                 const void* __restrict__ maskp,
                                                 const int* __restrict__ msflag,
                                                 const float* __restrict__ l1p,
                                                 const float* __restrict__ l2p,
                                                 unsigned short* __restrict__ TRh,
                                                 uint32_t* __restrict__ PMf) {
    __shared__ float s_tm[4], s_rm[4], s_ts[4], s_rs[4];
    __shared__ unsigned char s_nib[256];
    int row = blockIdx.x;               // b*S + q
    int t = threadIdx.x, w = t >> 6, l = t & 63;
    int ms = *msflag;
    size_t base = (size_t)row * NS;
    float4 r4 = ((const float4*)(rel + base))[t];
    float4 t4 = ((const float4*)(ts + base))[t];
    float rr[4], tt[4];
    *(float4*)rr = r4; *(float4*)tt = t4;
    float tv[4], rv[4];
    unsigned nib = 0;
    float tmx = -3.0e38f, rmx = -3.0e38f;
    #pragma unroll
    for (int j = 0; j < 4; j++) {
        bool m = mask_at(maskp, base + t * 4 + j, ms);
        nib |= (m ? 1u : 0u) << j;
        tv[j] = m ? -100000.0f : __expf(-fabsf(tt[j]));
        float rm_ = m ? rr[j] : 0.0f;
        rv[j] = (rm_ == 0.0f) ? -100000.0f : rm_;
        tmx = fmaxf(tmx, tv[j]); rmx = fmaxf(rmx, rv[j]);
    }
    s_nib[t] = (unsigned char)nib;
    #pragma unroll
    for (int off = 1; off < 64; off <<= 1) {
        tmx = fmaxf(tmx, __shfl_xor(tmx, off));
        rmx = fmaxf(rmx, __shfl_xor(rmx, off));
    }
    if (l == 0) { s_tm[w] = tmx; s_rm[w] = rmx; }
    __syncthreads();
    tmx = fmaxf(fmaxf(s_tm[0], s_tm[1]), fmaxf(s_tm[2], s_tm[3]));
    rmx = fmaxf(fmaxf(s_rm[0], s_rm[1]), fmaxf(s_rm[2], s_rm[3]));
    float te[4], re[4], tsum = 0.f, rsum = 0.f;
    #pragma unroll
    for (int j = 0; j < 4; j++) {
        te[j] = __expf(tv[j] - tmx); tsum += te[j];
        re[j] = __expf(rv[j] - rmx); rsum += re[j];
    }
    #pragma unroll
    for (int off = 1; off < 64; off <<= 1) {
        tsum += __shfl_xor(tsum, off);
        rsum += __shfl_xor(rsum, off);
    }
    if (l == 0) { s_ts[w] = tsum; s_rs[w] = rsum; }
    __syncthreads();
    tsum = s_ts[0] + s_ts[1] + s_ts[2] + s_ts[3];
    rsum = s_rs[0] + s_rs[1] + s_rs[2] + s_rs[3];
    float l1 = *l1p, l2 = *l2p;
    float ti = ((1.0f - l1) * l2) / tsum;
    float ri = l1 / rsum;
    u16x4 oh;
    oh[0] = f2h(te[0] * ti + re[0] * ri);
    oh[1] = f2h(te[1] * ti + re[1] * ri);
    oh[2] = f2h(te[2] * ti + re[2] * ri);
    oh[3] = f2h(te[3] * ti + re[3] * ri);
    int b = row >> 10, q = row & 1023;
    int qt = q >> 4, qr = q & 15;
    size_t slot = ((size_t)(b * 64 + qt) * 64 + (t >> 2)) * 64 + (qr + 16 * (t & 3));
    ((u16x4*)TRh)[slot] = oh;
    if (t < 32) {
        uint32_t word = 0;
        #pragma unroll
        for (int i = 0; i < 8; i++)
            word |= ((uint32_t)s_nib[t * 8 + i]) << (i * 4);
        PMf[((size_t)(b * 64 + qt) * 16 + qr) * 32 + t] = word;
    }
}

// Fused scores+softmax(no-max)+blend+PV, ONE WAVE per block, zero barriers, zero LDS.
// Dynamic loops (R14: full unroll spilled -> 2.4x scratch traffic). f16 TR.
// Pass 1: QK^T + exp -> row-sum. Pass 2: recompute + blend + prob store + PV.
// Swizzle: b pinned to XCD, qt innermost (R10 known-good locality).
__global__ __launch_bounds__(64, 4) void att_pv_kernel(const unsigned short* __restrict__ Qf,
                                                       const unsigned short* __restrict__ Kf,
                                                       const uint32_t* __restrict__ PMf,
                                                       const unsigned short* __restrict__ TRh,
                                                       const float* __restrict__ l1p,
                                                       const float* __restrict__ l2p,
                                                       const unsigned short* __restrict__ Vf,
                                                       float* __restrict__ probOut,
                                                       float* __restrict__ outp) {
    int bid = blockIdx.x;
    int swz = ((bid & 7) << 10) | (bid >> 3);   // XCD-aware, bijective (8192 = 8*1024)
    int qt = swz & 63;
    int h = (swz >> 6) & 15;
    int b = swz >> 10;
    int l = threadIdx.x, lr = l & 15, lg = l >> 4;
    int q0 = qt * 16;
    int q = q0 + lr;                   // this lane's q-row
    size_t bh = (size_t)(b * NH + h);

    const unsigned short* qf = Qf + (((bh * 64 + qt) * 2) * 64 + l) * 8;
    bf16x8 bq0 = *(const bf16x8*)(qf);
    bf16x8 bq1 = *(const bf16x8*)(qf + 64 * 8);

    const unsigned short* kfb = Kf + ((bh * 64 * 2) * 64) * 8 + (size_t)l * 8;
    const uint32_t* pmrow = PMf + ((size_t)(b * 64 + qt) * 16 + lr) * 32;

    // ---- pass 1: row sums ----
    float sm = 0.f;
    for (int t8 = 0; t8 < 8; t8++) {
        uint32_t pmw[4];
        *(uint4*)pmw = *(const uint4*)(pmrow + t8 * 4);
        #pragma unroll
        for (int tt = 0; tt < 8; tt++) {
            int t = t8 * 8 + tt;
            const unsigned short* kp = kfb + (size_t)t * 1024;
            bf16x8 a0 = *(const bf16x8*)kp;
            bf16x8 a1 = *(const bf16x8*)(kp + 512);
            f32x4 acc = {};
            acc = mfma32(a0, bq0, acc);
            acc = mfma32(a1, bq1, acc);
            uint32_t word = pmw[tt >> 1];
            int shift = (tt & 1) * 16 + lg * 4;
            #pragma unroll
            for (int r = 0; r < 4; r++) {
                bool m = (word >> (shift + r)) & 1u;
                sm += m ? 0.0f : __expf(acc[r] * 0.125f);
            }
        }
    }
    sm += __shfl_xor(sm, 16);
    sm += __shfl_xor(sm, 32);
    float l1 = *l1p, l2 = *l2p;
    float rinv = ((1.0f - l1) * (1.0f - l2)) / sm;

    // ---- pass 2: blend + prob store + PV ----
    float* po = probOut + bh * NS * NS + (size_t)q * NS;
    const u16x4* trh = (const u16x4*)TRh + ((size_t)(b * 64 + qt) * 64) * 64 + l;
    const unsigned short* vf = Vf + (bh * 32 * 4 * 64) * 8 + (size_t)l * 8;
    f32x4 acc2[4] = {};
    for (int tq = 0; tq < 8; tq++) {
        uint32_t pmw[4];
        *(uint4*)pmw = *(const uint4*)(pmrow + tq * 4);
        #pragma unroll
        for (int tpi = 0; tpi < 4; tpi++) {
            int tp = tq * 4 + tpi;
            bf16x4 pf0, pf1;
            #pragma unroll
            for (int hf = 0; hf < 2; hf++) {
                int t = tp * 2 + hf;
                const unsigned short* kp = kfb + (size_t)t * 1024;
                bf16x8 a0 = *(const bf16x8*)kp;
                bf16x8 a1 = *(const bf16x8*)(kp + 512);
                f32x4 acc = {};
                acc = mfma32(a0, bq0, acc);
                acc = mfma32(a1, bq1, acc);
                uint32_t word = pmw[tpi];
                int shift = hf * 16 + lg * 4;
                u16x4 tr4 = trh[(size_t)t * 64];
                float4 o;
                float e0 = ((word >> (shift + 0)) & 1u) ? 0.f : __expf(acc[0] * 0.125f);
                float e1 = ((word >> (shift + 1)) & 1u) ? 0.f : __expf(acc[1] * 0.125f);
                float e2 = ((word >> (shift + 2)) & 1u) ? 0.f : __expf(acc[2] * 0.125f);
                float e3 = ((word >> (shift + 3)) & 1u) ? 0.f : __expf(acc[3] * 0.125f);
                o.x = e0 * rinv + h2f(tr4[0]);
                o.y = e1 * rinv + h2f(tr4[1]);
                o.z = e2 * rinv + h2f(tr4[2]);
                o.w = e3 * rinv + h2f(tr4[3]);
                *(float4*)(po + t * 16 + lg * 4) = o;
                bf16x4 pk;
                pk[0] = (short)f2bf(o.x); pk[1] = (short)f2bf(o.y);
                pk[2] = (short)f2bf(o.z); pk[3] = (short)f2bf(o.w);
                if (hf == 0) pf0 = pk; else pf1 = pk;
            }
            #pragma unroll
            for (int dt = 0; dt < 4; dt++) {
                bf16x8 vv = *(const bf16x8*)(vf + (size_t)(tp * 4 + dt) * 512);
                bf16x4 v0 = __builtin_shufflevector(vv, vv, 0, 1, 2, 3);
                bf16x4 v1 = __builtin_shufflevector(vv, vv, 4, 5, 6, 7);
                acc2[dt] = mfma16(v0, pf0, acc2[dt]);
                acc2[dt] = mfma16(v1, pf1, acc2[dt]);
            }
        }
    }
    // out: d = dt*16 + lg*4 + r, row q
    float* orow = outp + ((size_t)b * NS + q) * ND + h * NHD + lg * 4;
    #pragma unroll
    for (int dt = 0; dt < 4; dt++) {
        float4 ov;
        ov.x = acc2[dt][0]; ov.y = acc2[dt][1]; ov.z = acc2[dt][2]; ov.w = acc2[dt][3];
        *(float4*)(orow + dt * 16) = ov;
    }
}

extern "C" void kernel_launch(void* const* d_in, const int* in_sizes, int n_in,
                              void* d_out, int out_size, void* d_ws, size_t ws_size,
                              hipStream_t stream) {
    const float* query = (const float*)d_in[0];
    const float* key   = (const float*)d_in[1];
    const float* value = (const float*)d_in[2];
    const float* rel   = (const float*)d_in[3];
    const float* ts    = (const float*)d_in[4];
    const void*  mask  = d_in[5];
    const float* l1p   = (const float*)d_in[6];
    const float* l2p   = (const float*)d_in[7];
    const float* Wq = (const float*)d_in[9];
    const float* bq = (const float*)d_in[10];
    const float* Wk = (const float*)d_in[11];
    const float* bk = (const float*)d_in[12];
    const float* Wv = (const float*)d_in[13];
    const float* bv = (const float*)d_in[14];

    char* ws = (char*)d_ws;
    const size_t SZ = (size_t)NB * NS * ND * 2;   // 16.78 MB
    unsigned short* Qf  = (unsigned short*)(ws);
    unsigned short* Kf  = (unsigned short*)(ws + SZ);
    unsigned short* Vf  = (unsigned short*)(ws + 2 * SZ);
    unsigned short* Afq = (unsigned short*)(ws + 3 * SZ);
    unsigned short* Afk = (unsigned short*)(ws + 4 * SZ);
    unsigned short* Afv = (unsigned short*)(ws + 5 * SZ);
    unsigned short* Wfq = (unsigned short*)(ws + 6 * SZ);
    unsigned short* Wfk = (unsigned short*)(ws + 6 * SZ + 2u * 1024 * 1024);
    unsigned short* Wfv = (unsigned short*)(ws + 6 * SZ + 4u * 1024 * 1024);
    int* msflag         = (int*)(ws + 6 * SZ + 6u * 1024 * 1024);
    uint32_t* PMf       = (uint32_t*)(ws + 6 * SZ + 8u * 1024 * 1024);  // 1 MB
    // TRh (f16, 16.78 MB = SZ) reuses Afq — written only AFTER projections finish.
    unsigned short* TRh = (unsigned short*)(ws + 3 * SZ);

    detect_mask<<<1, 64, 0, stream>>>((const unsigned int*)mask, msflag);

    const int nuX = NB * NS * 2;      // 16384 units (M=8192)
    const int nuW = 1024 * 2;         // 2048 units  (M=1024)
    cvt_frag<<<512, 256, 0, stream>>>(query, Afq, nuX);
    cvt_frag<<<512, 256, 0, stream>>>(key,   Afk, nuX);
    cvt_frag<<<512, 256, 0, stream>>>(value, Afv, nuX);
    cvt_frag<<<128, 256, 0, stream>>>(Wq, Wfq, nuW);
    cvt_frag<<<128, 256, 0, stream>>>(Wk, Wfk, nuW);
    cvt_frag<<<128, 256, 0, stream>>>(Wv, Wfv, nuW);

    dim3 pg(8, 64);   // x = n-panel, y = m-panel (Wf pinned per XCD)
    proj_gemm<<<pg, 256, 0, stream>>>(Afq, Wfq, bq, Qf, 0);
    proj_gemm<<<pg, 256, 0, stream>>>(Afk, Wfk, bk, Kf, 0);
    proj_gemm<<<pg, 256, 0, stream>>>(Afv, Wfv, bv, Vf, 1);

    tr_kernel<<<NB * NS, 256, 0, stream>>>(rel, ts, mask, msflag, l1p, l2p, TRh, PMf);

    float* outp = (float*)d_out;
    float* probOut = outp + (size_t)NB * NS * ND;
    att_pv_kernel<<<NB * NH * (NS / 16), 64, 0, stream>>>(Qf, Kf, PMf, TRh, l1p, l2p, Vf,
                                                          probOut, outp);
}